// Round 20
// baseline (274.086 us; speedup 1.0000x reference)
//
#include <hip/hip_runtime.h>
#include <hip/hip_fp16.h>
#include <math.h>

#define N_OBS_C 2000000
#define N_REFL_C 250000
#define N_IMG_C 2000
#define MC_C 32
#define HID 64
#define NSLOT 16
#define LOG2PI_F 1.8378770664093453f

// ---------------- workspace layout (bytes) ----------------
// [0,64)        accs: 8 doubles (kl, llmax, W, Sx, Sy, Sxx, Syy, Sxy)
// [64,1536064)  img_mom [2000][12][NSLOT] float  (zeroed by k_zero)
// [2097152,..)  sq [250000] float
// [4194304,..)  img_pre [2000][64] float
// [8388608,..)  zT [250000][32] __half (16MB)

typedef float f2 __attribute__((ext_vector_type(2)));

__device__ __forceinline__ void pkfma(f2& d, f2 a, f2 b) {
    asm("v_pk_fma_f32 %0, %1, %2, %0" : "+v"(d) : "v"(a), "v"(b));
}
__device__ __forceinline__ f2 pkfma3(f2 a, f2 b, f2 c) {
    f2 d;
    asm("v_pk_fma_f32 %0, %1, %2, %3" : "=v"(d) : "v"(a), "v"(b), "v"(c));
    return d;
}

__device__ __forceinline__ float softplusf(float x) {
    return (x > 20.f) ? x : log1pf(expf(x));
}

// ---- K0: zero the accumulator region ----
#define ZERO_F4 96004
__global__ __launch_bounds__(256) void k_zero(float4* __restrict__ p) {
    int i = blockIdx.x * 256 + threadIdx.x;
    if (i < ZERO_F4) p[i] = make_float4(0.f, 0.f, 0.f, 0.f);
}

// ---- K1: per-reflection: sq, KL partial, fp16 zT table ----
__global__ __launch_bounds__(256) void k_refl(const float* __restrict__ q_loc,
                                              const float* __restrict__ q_scale_raw,
                                              const float* __restrict__ zeps,
                                              float* __restrict__ sq,
                                              __half* __restrict__ zT,
                                              double* __restrict__ kl_sum) {
    int r = blockIdx.x * 256 + threadIdx.x;
    double kl = 0.0;
    if (r < N_REFL_C) {
        float ql = q_loc[r];
        float sp = softplusf(q_scale_raw[r]);
        sq[r] = sp;
        kl = (double)(-logf(sp) + 0.5f * (sp * sp + ql * ql) - 0.5f);
        float z[MC_C];
#pragma unroll
        for (int m = 0; m < MC_C; ++m)
            z[m] = fmaf(sp, zeps[(size_t)m * N_REFL_C + r], ql);
        uint4* outp = (uint4*)(zT + (size_t)r * MC_C);
#pragma unroll
        for (int q = 0; q < 4; ++q) {
            __half2 h0 = __floats2half2_rn(z[8 * q + 0], z[8 * q + 1]);
            __half2 h1 = __floats2half2_rn(z[8 * q + 2], z[8 * q + 3]);
            __half2 h2 = __floats2half2_rn(z[8 * q + 4], z[8 * q + 5]);
            __half2 h3 = __floats2half2_rn(z[8 * q + 6], z[8 * q + 7]);
            outp[q] = make_uint4(*(unsigned*)&h0, *(unsigned*)&h1,
                                 *(unsigned*)&h2, *(unsigned*)&h3);
        }
    }
    for (int o = 32; o > 0; o >>= 1) kl += __shfl_xor(kl, o);
    __shared__ double skl[4];
    int lane = threadIdx.x & 63, w = threadIdx.x >> 6;
    if (lane == 0) skl[w] = kl;
    __syncthreads();
    if (threadIdx.x == 0) atomicAdd(kl_sum, skl[0] + skl[1] + skl[2] + skl[3]);
}

// ---- K1b: per-image precompute ----
__global__ __launch_bounds__(64) void k_imgpre(const float* __restrict__ img_emb,
                                               const float* __restrict__ W1,
                                               const float* __restrict__ b1,
                                               float* __restrict__ img_pre) {
    int g = blockIdx.x;
    int j = threadIdx.x;
    float acc = b1[j];
#pragma unroll
    for (int e = 0; e < 32; ++e)
        acc = fmaf(img_emb[g * 32 + e], W1[(12 + e) * HID + j], acc);
    img_pre[g * HID + j] = acc;
}

// ---- K2: FUSED MLP(2 obs/thread) + MC, block = 512 obs ----
__global__ __launch_bounds__(256) void k_main(const float* __restrict__ I,
                                              const float* __restrict__ SigI,
                                              const int* __restrict__ image_id,
                                              const float* __restrict__ metadata,
                                              const float* __restrict__ wavelength,
                                              const float* __restrict__ dHKL,
                                              const int* __restrict__ refl_ids,
                                              const float* __restrict__ q_loc,
                                              const float* __restrict__ W1,
                                              const float* __restrict__ W2,
                                              const float* __restrict__ b2,
                                              const float* __restrict__ sq,
                                              const float* __restrict__ img_pre,
                                              const float* __restrict__ seps,
                                              const __half* __restrict__ zT,
                                              float* __restrict__ img_mom) {
    __shared__ float sW1[12 * HID];
    __shared__ float sW2a[HID], sW2b[HID];
    __shared__ float4 pms[512];
    __shared__ float2 sIS[512];
    __shared__ int2 srid[512];
    __shared__ int sgid[512];
    __shared__ float mom[8][32][12];
    __shared__ int sflag[16];

    int tid = threadIdx.x;
    for (int t = tid; t < 12 * HID; t += 256) sW1[t] = W1[t];
    if (tid < HID) {
        sW2a[tid] = W2[tid * 2 + 0];
        sW2b[tid] = W2[tid * 2 + 1];
    }

    // ---------- scalar loads for 2 obs ----------
    int n0 = blockIdx.x * 512 + tid;
    int n1 = n0 + 256;
    bool a0 = (n0 < N_OBS_C), a1 = (n1 < N_OBS_C);
    int m0 = a0 ? n0 : (N_OBS_C - 1);
    int m1 = a1 ? n1 : (N_OBS_C - 1);

    float I0 = I[m0], I1 = I[m1];
    float S0 = SigI[m0], S1 = SigI[m1];
    f2 f0p[10], f1p[10];
    {
        float v;
        f0p[0].x = I0; f0p[0].y = I0;
        f0p[1].x = S0; f0p[1].y = S0;
#pragma unroll
        for (int i = 0; i < 6; ++i) {
            v = metadata[(size_t)m0 * 6 + i];
            f0p[2 + i].x = v; f0p[2 + i].y = v;
        }
        v = wavelength[m0];   f0p[8].x = v; f0p[8].y = v;
        float dh = dHKL[m0];
        v = 1.0f / (dh * dh); f0p[9].x = v; f0p[9].y = v;

        f1p[0].x = I1; f1p[0].y = I1;
        f1p[1].x = S1; f1p[1].y = S1;
#pragma unroll
        for (int i = 0; i < 6; ++i) {
            v = metadata[(size_t)m1 * 6 + i];
            f1p[2 + i].x = v; f1p[2 + i].y = v;
        }
        v = wavelength[m1];   f1p[8].x = v; f1p[8].y = v;
        dh = dHKL[m1];
        v = 1.0f / (dh * dh); f1p[9].x = v; f1p[9].y = v;
    }
    int g0 = image_id[m0], g1 = image_id[m1];
    int r00 = refl_ids[m0], r01 = refl_ids[N_OBS_C + m0];
    int r10 = refl_ids[m1], r11 = refl_ids[N_OBS_C + m1];
    f2 qa0p, sa0p, qb0p, sb0p, qa1p, sa1p, qb1p, sb1p;
    { float v;
      v = q_loc[r00]; qa0p.x = v; qa0p.y = v;
      v = sq[r00];    sa0p.x = v; sa0p.y = v;
      v = q_loc[r01]; qb0p.x = v; qb0p.y = v;
      v = sq[r01];    sb0p.x = v; sb0p.y = v;
      v = q_loc[r10]; qa1p.x = v; qa1p.y = v;
      v = sq[r10];    sa1p.x = v; sa1p.y = v;
      v = q_loc[r11]; qb1p.x = v; qb1p.y = v;
      v = sq[r11];    sb1p.x = v; sb1p.y = v;
    }
    const float* ip0 = img_pre + (size_t)g0 * HID;
    const float* ip1 = img_pre + (size_t)g1 * HID;

    sIS[tid] = make_float2(I0, S0);
    sIS[tid + 256] = make_float2(I1, S1);
    srid[tid] = make_int2(r00, r01);
    srid[tid + 256] = make_int2(r10, r11);
    sgid[tid] = a0 ? g0 : -1;
    sgid[tid + 256] = a1 ? g1 : -1;

    __syncthreads();   // sW1/sW2 + scalar tables ready

    // ---------- Phase A: 2-obs MLP ----------
    f2 lA00 = {0.f, 0.f}, lA01 = {0.f, 0.f}, lB00 = {0.f, 0.f}, lB01 = {0.f, 0.f};
    f2 lA10 = {0.f, 0.f}, lA11 = {0.f, 0.f}, lB10 = {0.f, 0.f}, lB11 = {0.f, 0.f};

#pragma unroll 1
    for (int jt = 0; jt < HID; jt += 8) {
        f2 ac0[4], ac1[4];
        {
            float4 pa = *(const float4*)&ip0[jt];
            float4 pb = *(const float4*)&ip0[jt + 4];
            ac0[0].x = pa.x; ac0[0].y = pa.y;
            ac0[1].x = pa.z; ac0[1].y = pa.w;
            ac0[2].x = pb.x; ac0[2].y = pb.y;
            ac0[3].x = pb.z; ac0[3].y = pb.w;
            pa = *(const float4*)&ip1[jt];
            pb = *(const float4*)&ip1[jt + 4];
            ac1[0].x = pa.x; ac1[0].y = pa.y;
            ac1[1].x = pa.z; ac1[1].y = pa.w;
            ac1[2].x = pb.x; ac1[2].y = pb.y;
            ac1[3].x = pb.z; ac1[3].y = pb.w;
        }
#pragma unroll
        for (int i = 0; i < 10; ++i) {
            float4 wa = *(const float4*)&sW1[(i + 2) * HID + jt];
            float4 wb = *(const float4*)&sW1[(i + 2) * HID + jt + 4];
            f2 w0; w0.x = wa.x; w0.y = wa.y;
            f2 w1; w1.x = wa.z; w1.y = wa.w;
            f2 w2; w2.x = wb.x; w2.y = wb.y;
            f2 w3; w3.x = wb.z; w3.y = wb.w;
            pkfma(ac0[0], f0p[i], w0); pkfma(ac1[0], f1p[i], w0);
            pkfma(ac0[1], f0p[i], w1); pkfma(ac1[1], f1p[i], w1);
            pkfma(ac0[2], f0p[i], w2); pkfma(ac1[2], f1p[i], w2);
            pkfma(ac0[3], f0p[i], w3); pkfma(ac1[3], f1p[i], w3);
        }
        f2 w0p[4], w1p[4], vap[4], vbp[4];
        {
            float4 wa = *(const float4*)&sW1[jt];
            float4 wb = *(const float4*)&sW1[jt + 4];
            w0p[0].x = wa.x; w0p[0].y = wa.y;
            w0p[1].x = wa.z; w0p[1].y = wa.w;
            w0p[2].x = wb.x; w0p[2].y = wb.y;
            w0p[3].x = wb.z; w0p[3].y = wb.w;
            wa = *(const float4*)&sW1[HID + jt];
            wb = *(const float4*)&sW1[HID + jt + 4];
            w1p[0].x = wa.x; w1p[0].y = wa.y;
            w1p[1].x = wa.z; w1p[1].y = wa.w;
            w1p[2].x = wb.x; w1p[2].y = wb.y;
            w1p[3].x = wb.z; w1p[3].y = wb.w;
            wa = *(const float4*)&sW2a[jt];
            wb = *(const float4*)&sW2a[jt + 4];
            vap[0].x = wa.x; vap[0].y = wa.y;
            vap[1].x = wa.z; vap[1].y = wa.w;
            vap[2].x = wb.x; vap[2].y = wb.y;
            vap[3].x = wb.z; vap[3].y = wb.w;
            wa = *(const float4*)&sW2b[jt];
            wb = *(const float4*)&sW2b[jt + 4];
            vbp[0].x = wa.x; vbp[0].y = wa.y;
            vbp[1].x = wa.z; vbp[1].y = wa.w;
            vbp[2].x = wb.x; vbp[2].y = wb.y;
            vbp[3].x = wb.z; vbp[3].y = wb.w;
        }
#pragma unroll
        for (int k = 0; k < 4; ++k) {
            f2 h;
            h = pkfma3(sa0p, w1p[k], ac0[k]);
            pkfma(h, qa0p, w0p[k]);
            h.x = fmaxf(h.x, 0.f); h.y = fmaxf(h.y, 0.f);
            pkfma(lA00, h, vap[k]);
            pkfma(lA01, h, vbp[k]);
            h = pkfma3(sb0p, w1p[k], ac0[k]);
            pkfma(h, qb0p, w0p[k]);
            h.x = fmaxf(h.x, 0.f); h.y = fmaxf(h.y, 0.f);
            pkfma(lB00, h, vap[k]);
            pkfma(lB01, h, vbp[k]);
            h = pkfma3(sa1p, w1p[k], ac1[k]);
            pkfma(h, qa1p, w0p[k]);
            h.x = fmaxf(h.x, 0.f); h.y = fmaxf(h.y, 0.f);
            pkfma(lA10, h, vap[k]);
            pkfma(lA11, h, vbp[k]);
            h = pkfma3(sb1p, w1p[k], ac1[k]);
            pkfma(h, qb1p, w0p[k]);
            h.x = fmaxf(h.x, 0.f); h.y = fmaxf(h.y, 0.f);
            pkfma(lB10, h, vap[k]);
            pkfma(lB11, h, vbp[k]);
        }
    }

    {
        float bb0 = b2[0], bb1 = b2[1];
        pms[tid] = make_float4(bb0 + lA00.x + lA00.y, softplusf(bb1 + lA01.x + lA01.y),
                               bb0 + lB00.x + lB00.y, softplusf(bb1 + lB01.x + lB01.y));
        pms[tid + 256] = make_float4(bb0 + lA10.x + lA10.y, softplusf(bb1 + lA11.x + lA11.y),
                                     bb0 + lB10.x + lB10.y, softplusf(bb1 + lB11.x + lB11.y));
    }
    __syncthreads();

    if (tid < 16) sflag[tid] = (sgid[tid * 32] == sgid[tid * 32 + 31]) ? 1 : 0;
    __syncthreads();

    // ---------- Phase B: 16 chunks of 32 obs, two flush passes ----------
    int grp = tid >> 3;
    int m4 = tid & 7;

    for (int half = 0; half < 2; ++half) {
#pragma unroll 2
        for (int cc = 0; cc < 8; ++cc) {
            int c = half * 8 + cc;
            int o = c * 32 + grp;
            int nn = blockIdx.x * 512 + o;
            if (nn >= N_OBS_C) nn = N_OBS_C - 1;
            int2 rr = srid[o];
            float4 pp = pms[o];
            float2 IS = sIS[o];

            float4 ss = *(const float4*)&seps[(size_t)nn * MC_C + m4 * 4];
            float4 z0, z1;
            {
                const __half2* zp = (const __half2*)(zT + (size_t)rr.x * MC_C + m4 * 4);
                __half2 h0 = zp[0], h1 = zp[1];
                float2 fa = __half22float2(h0), fb = __half22float2(h1);
                z0 = make_float4(fa.x, fa.y, fb.x, fb.y);
                zp = (const __half2*)(zT + (size_t)rr.y * MC_C + m4 * 4);
                h0 = zp[0]; h1 = zp[1];
                fa = __half22float2(h0); fb = __half22float2(h1);
                z1 = make_float4(fa.x, fa.y, fb.x, fb.y);
            }

            float rsig = 1.0f / IS.y;
            float mnIr = -IS.x * rsig;

            float sd20 = 0.f, sip0 = 0.f, sd21 = 0.f, sip1 = 0.f;
#define MCSTEP(zc0, zc1, sc_)                              \
            {                                              \
                float sc0 = fmaf(pp.y, sc_, pp.x);         \
                float ip0 = zc0 * sc0;                     \
                float d0 = fmaf(ip0, rsig, mnIr);          \
                sd20 = fmaf(d0, d0, sd20);                 \
                sip0 += ip0;                               \
                float sc1 = fmaf(pp.w, sc_, pp.z);         \
                float ip1 = zc1 * sc1;                     \
                float d1 = fmaf(ip1, rsig, mnIr);          \
                sd21 = fmaf(d1, d1, sd21);                 \
                sip1 += ip1;                               \
            }
            MCSTEP(z0.x, z1.x, ss.x)
            MCSTEP(z0.y, z1.y, ss.y)
            MCSTEP(z0.z, z1.z, ss.z)
            MCSTEP(z0.w, z1.w, ss.w)
#undef MCSTEP

#pragma unroll
            for (int o2 = 4; o2 > 0; o2 >>= 1) {
                sd20 += __shfl_xor(sd20, o2);
                sd21 += __shfl_xor(sd21, o2);
                sip0 += __shfl_xor(sip0, o2);
                sip1 += __shfl_xor(sip1, o2);
            }

            if (m4 == 0) {
                float logS32 = 32.f * logf(IS.y) + 16.f * LOG2PI_F;
                float y0 = sip0 * (1.0f / 32.0f);
                float y1 = sip1 * (1.0f / 32.0f);
                float w = rsig * rsig;
                float* mr = mom[cc][grp];
                mr[0] = -0.5f * sd20 - logS32;
                mr[1] = -0.5f * sd21 - logS32;
                mr[2] = w;
                mr[3] = w * IS.x;
                mr[4] = w * IS.x * IS.x;
                mr[5] = w * y0;
                mr[6] = w * y0 * y0;
                mr[7] = w * IS.x * y0;
                mr[8] = w * y1;
                mr[9] = w * y1 * y1;
                mr[10] = w * IS.x * y1;
                mr[11] = 0.f;
            }
        }
        __syncthreads();

        // flush: 96 threads = 8 chunks x 12 moments
        if (tid < 96) {
            int cc = tid / 12, j = tid - cc * 12;
            int c = half * 8 + cc;
            int slot = blockIdx.x & (NSLOT - 1);
            if (sflag[c]) {
                int gg = sgid[c * 32];
                if (gg >= 0) {
                    float v = 0.f;
#pragma unroll
                    for (int s = 0; s < 32; ++s) v += mom[cc][s][j];
                    atomicAdd(&img_mom[(gg * 12 + j) * NSLOT + slot], v);
                }
            } else {
                for (int s = 0; s < 32; ++s) {
                    int gs = sgid[c * 32 + s];
                    if (gs >= 0)
                        atomicAdd(&img_mom[(gs * 12 + j) * NSLOT + slot], mom[cc][s][j]);
                }
            }
        }
        __syncthreads();
    }
}

// ---- K3: per-image slot-sum + argmax + block-reduced global sums ----
__global__ __launch_bounds__(256) void k_img(const float* __restrict__ img_mom,
                                             double* __restrict__ accs) {
    int g = blockIdx.x * 256 + threadIdx.x;
    double red7[7] = {0, 0, 0, 0, 0, 0, 0};
    if (g < N_IMG_C) {
        float M[12];
#pragma unroll
        for (int j = 0; j < 12; ++j) {
            const float4* p = (const float4*)&img_mom[(g * 12 + j) * NSLOT];
            float4 q0 = p[0], q1 = p[1], q2 = p[2], q3 = p[3];
            M[j] = (q0.x + q0.y + q0.z + q0.w) + (q1.x + q1.y + q1.z + q1.w) +
                   (q2.x + q2.y + q2.z + q2.w) + (q3.x + q3.y + q3.z + q3.w);
        }
        float ll0 = M[0] * (1.0f / 32.0f);
        float ll1 = M[1] * (1.0f / 32.0f);
        bool op1 = (ll1 > ll0);
        red7[0] = (double)fmaxf(ll0, ll1);
        red7[1] = (double)M[2];
        red7[2] = (double)M[3];
        red7[3] = (double)(op1 ? M[8] : M[5]);
        red7[4] = (double)M[4];
        red7[5] = (double)(op1 ? M[9] : M[6]);
        red7[6] = (double)(op1 ? M[10] : M[7]);
    }
#pragma unroll
    for (int k = 0; k < 7; ++k)
        for (int o = 32; o > 0; o >>= 1) red7[k] += __shfl_xor(red7[k], o);
    __shared__ double sred[4][7];
    int lane = threadIdx.x & 63, w = threadIdx.x >> 6;
    if (lane == 0) {
#pragma unroll
        for (int k = 0; k < 7; ++k) sred[w][k] = red7[k];
    }
    __syncthreads();
    if (threadIdx.x < 7) {
        double v = sred[0][threadIdx.x] + sred[1][threadIdx.x] +
                   sred[2][threadIdx.x] + sred[3][threadIdx.x];
        atomicAdd(&accs[1 + threadIdx.x], v);
    }
}

// ---- K5: finalize ----
__global__ void k_final(const double* __restrict__ accs, float* __restrict__ out) {
    double kl = accs[0] / (double)N_REFL_C;
    double elbo = -(accs[1] / (double)N_IMG_C) + 1.0 * kl;
    double W = accs[2], Sx = accs[3], Sy = accs[4];
    double Sxx = accs[5], Syy = accs[6], Sxy = accs[7];
    double z = 1.0 / W;
    double mx = z * Sx, my = z * Sy;
    double cxy = z * Sxy - mx * my;
    double cx = z * Sxx - mx * mx;
    double cy = z * Syy - my * my;
    double cc = cxy / sqrt(cx * cy);
    out[0] = (float)elbo;
    out[1] = (float)cc;
}

extern "C" void kernel_launch(void* const* d_in, const int* in_sizes, int n_in,
                              void* d_out, int out_size, void* d_ws, size_t ws_size,
                              hipStream_t stream) {
    const float* I = (const float*)d_in[0];
    const float* SigI = (const float*)d_in[1];
    const int* image_id = (const int*)d_in[2];
    const float* metadata = (const float*)d_in[3];
    const float* wavelength = (const float*)d_in[4];
    const float* dHKL = (const float*)d_in[5];
    const int* refl_ids = (const int*)d_in[6];
    const float* q_loc = (const float*)d_in[7];
    const float* q_scale_raw = (const float*)d_in[8];
    const float* img_emb = (const float*)d_in[9];
    const float* W1 = (const float*)d_in[10];
    const float* b1 = (const float*)d_in[11];
    const float* W2 = (const float*)d_in[12];
    const float* b2 = (const float*)d_in[13];
    const float* zeps = (const float*)d_in[14];
    const float* seps = (const float*)d_in[15];
    float* out = (float*)d_out;

    char* ws = (char*)d_ws;
    double* accs = (double*)ws;
    float* img_mom = (float*)(ws + 64);
    float* sqv = (float*)(ws + 2097152);
    float* img_pre = (float*)(ws + 4194304);
    __half* zT = (__half*)(ws + 8388608);

    k_zero<<<(ZERO_F4 + 255) / 256, 256, 0, stream>>>((float4*)ws);
    k_refl<<<(N_REFL_C + 255) / 256, 256, 0, stream>>>(q_loc, q_scale_raw, zeps,
                                                       sqv, zT, &accs[0]);
    k_imgpre<<<N_IMG_C, 64, 0, stream>>>(img_emb, W1, b1, img_pre);
    k_main<<<(N_OBS_C + 511) / 512, 256, 0, stream>>>(I, SigI, image_id, metadata,
                                                      wavelength, dHKL, refl_ids,
                                                      q_loc, W1, W2, b2, sqv,
                                                      img_pre, seps, zT, img_mom);
    k_img<<<(N_IMG_C + 255) / 256, 256, 0, stream>>>(img_mom, accs);
    k_final<<<1, 1, 0, stream>>>(accs, out);
}

// Round 21
// 233.032 us; speedup vs baseline: 1.1762x; 1.1762x over previous
//
#include <hip/hip_runtime.h>
#include <hip/hip_fp16.h>
#include <math.h>

#define N_OBS_C 2000000
#define N_REFL_C 250000
#define N_IMG_C 2000
#define MC_C 32
#define HID 64
#define NSLOT 16
#define LOG2PI_F 1.8378770664093453f

// ---------------- workspace layout (bytes) ----------------
// [0,64)        accs: 8 doubles (kl, llmax, W, Sx, Sy, Sxx, Syy, Sxy)
// [64,1536064)  img_mom [2000][12][NSLOT] float  (zeroed by k_zero)
// [2097152,..)  sq [250000] float
// [4194304,..)  img_pre [2000][64] float
// [8388608,..)  zT [250000][32] __half (16MB)

typedef float f2 __attribute__((ext_vector_type(2)));

__device__ __forceinline__ void pkfma(f2& d, f2 a, f2 b) {
    asm("v_pk_fma_f32 %0, %1, %2, %0" : "+v"(d) : "v"(a), "v"(b));
}
__device__ __forceinline__ f2 pkfma3(f2 a, f2 b, f2 c) {
    f2 d;
    asm("v_pk_fma_f32 %0, %1, %2, %3" : "=v"(d) : "v"(a), "v"(b), "v"(c));
    return d;
}

__device__ __forceinline__ float softplusf(float x) {
    return (x > 20.f) ? x : log1pf(expf(x));
}

// ---- K0: zero the accumulator region ----
#define ZERO_F4 96004
__global__ __launch_bounds__(256) void k_zero(float4* __restrict__ p) {
    int i = blockIdx.x * 256 + threadIdx.x;
    if (i < ZERO_F4) p[i] = make_float4(0.f, 0.f, 0.f, 0.f);
}

// ---- K1: per-reflection: sq, KL partial, fp16 zT table ----
__global__ __launch_bounds__(256) void k_refl(const float* __restrict__ q_loc,
                                              const float* __restrict__ q_scale_raw,
                                              const float* __restrict__ zeps,
                                              float* __restrict__ sq,
                                              __half* __restrict__ zT,
                                              double* __restrict__ kl_sum) {
    int r = blockIdx.x * 256 + threadIdx.x;
    double kl = 0.0;
    if (r < N_REFL_C) {
        float ql = q_loc[r];
        float sp = softplusf(q_scale_raw[r]);
        sq[r] = sp;
        kl = (double)(-logf(sp) + 0.5f * (sp * sp + ql * ql) - 0.5f);
        float z[MC_C];
#pragma unroll
        for (int m = 0; m < MC_C; ++m)
            z[m] = fmaf(sp, zeps[(size_t)m * N_REFL_C + r], ql);
        uint4* outp = (uint4*)(zT + (size_t)r * MC_C);
#pragma unroll
        for (int q = 0; q < 4; ++q) {
            __half2 h0 = __floats2half2_rn(z[8 * q + 0], z[8 * q + 1]);
            __half2 h1 = __floats2half2_rn(z[8 * q + 2], z[8 * q + 3]);
            __half2 h2 = __floats2half2_rn(z[8 * q + 4], z[8 * q + 5]);
            __half2 h3 = __floats2half2_rn(z[8 * q + 6], z[8 * q + 7]);
            outp[q] = make_uint4(*(unsigned*)&h0, *(unsigned*)&h1,
                                 *(unsigned*)&h2, *(unsigned*)&h3);
        }
    }
    for (int o = 32; o > 0; o >>= 1) kl += __shfl_xor(kl, o);
    __shared__ double skl[4];
    int lane = threadIdx.x & 63, w = threadIdx.x >> 6;
    if (lane == 0) skl[w] = kl;
    __syncthreads();
    if (threadIdx.x == 0) atomicAdd(kl_sum, skl[0] + skl[1] + skl[2] + skl[3]);
}

// ---- K1b: per-image precompute ----
__global__ __launch_bounds__(64) void k_imgpre(const float* __restrict__ img_emb,
                                               const float* __restrict__ W1,
                                               const float* __restrict__ b1,
                                               float* __restrict__ img_pre) {
    int g = blockIdx.x;
    int j = threadIdx.x;
    float acc = b1[j];
#pragma unroll
    for (int e = 0; e < 32; ++e)
        acc = fmaf(img_emb[g * 32 + e], W1[(12 + e) * HID + j], acc);
    img_pre[g * HID + j] = acc;
}

// ---- K2: FUSED MLP + MC per block of 256 obs (no LDS atomics) ----
__global__ __launch_bounds__(256) void k_main(const float* __restrict__ I,
                                              const float* __restrict__ SigI,
                                              const int* __restrict__ image_id,
                                              const float* __restrict__ metadata,
                                              const float* __restrict__ wavelength,
                                              const float* __restrict__ dHKL,
                                              const int* __restrict__ refl_ids,
                                              const float* __restrict__ q_loc,
                                              const float* __restrict__ W1,
                                              const float* __restrict__ W2,
                                              const float* __restrict__ b2,
                                              const float* __restrict__ sq,
                                              const float* __restrict__ img_pre,
                                              const float* __restrict__ seps,
                                              const __half* __restrict__ zT,
                                              float* __restrict__ img_mom) {
    __shared__ float sW1[12 * HID];
    __shared__ float sW2a[HID], sW2b[HID];
    __shared__ float4 pms[256];
    __shared__ float2 sIS[256];
    __shared__ int2 srid[256];
    __shared__ int sgid[256];
    __shared__ float mom[8][32][12];
    __shared__ int sflag[8];

    int tid = threadIdx.x;
    for (int t = tid; t < 12 * HID; t += 256) sW1[t] = W1[t];
    if (tid < HID) {
        sW2a[tid] = W2[tid * 2 + 0];
        sW2b[tid] = W2[tid * 2 + 1];
    }

    // ---------- Phase A: per-thread MLP (1 obs/thread) ----------
    int n = blockIdx.x * 256 + tid;
    bool act = (n < N_OBS_C);
    int m = act ? n : (N_OBS_C - 1);

    float Inv = I[m];
    float Snv = SigI[m];
    f2 fp[10];
    {
        float v;
        fp[0].x = Inv; fp[0].y = Inv;
        fp[1].x = Snv; fp[1].y = Snv;
#pragma unroll
        for (int i = 0; i < 6; ++i) {
            v = metadata[(size_t)m * 6 + i];
            fp[2 + i].x = v; fp[2 + i].y = v;
        }
        v = wavelength[m]; fp[8].x = v; fp[8].y = v;
        float dh = dHKL[m];
        v = 1.0f / (dh * dh); fp[9].x = v; fp[9].y = v;
    }
    int g = image_id[m];
    int r0 = refl_ids[m];
    int r1 = refl_ids[N_OBS_C + m];
    f2 qa, sa, qb, sb;
    { float v;
      v = q_loc[r0]; qa.x = v; qa.y = v;
      v = sq[r0];    sa.x = v; sa.y = v;
      v = q_loc[r1]; qb.x = v; qb.y = v;
      v = sq[r1];    sb.x = v; sb.y = v;
    }
    const float* ipg = img_pre + (size_t)g * HID;

    __syncthreads();   // sW1/sW2 ready

    f2 lA0 = {0.f, 0.f}, lA1 = {0.f, 0.f}, lB0 = {0.f, 0.f}, lB1 = {0.f, 0.f};

#pragma unroll 1
    for (int jt = 0; jt < HID; jt += 8) {
        f2 ac[4];
        {
            float4 pa = *(const float4*)&ipg[jt];
            float4 pb = *(const float4*)&ipg[jt + 4];
            ac[0].x = pa.x; ac[0].y = pa.y;
            ac[1].x = pa.z; ac[1].y = pa.w;
            ac[2].x = pb.x; ac[2].y = pb.y;
            ac[3].x = pb.z; ac[3].y = pb.w;
        }
#pragma unroll
        for (int i = 0; i < 10; ++i) {
            float4 wa = *(const float4*)&sW1[(i + 2) * HID + jt];
            float4 wb = *(const float4*)&sW1[(i + 2) * HID + jt + 4];
            f2 w0; w0.x = wa.x; w0.y = wa.y;
            f2 w1; w1.x = wa.z; w1.y = wa.w;
            f2 w2; w2.x = wb.x; w2.y = wb.y;
            f2 w3; w3.x = wb.z; w3.y = wb.w;
            pkfma(ac[0], fp[i], w0);
            pkfma(ac[1], fp[i], w1);
            pkfma(ac[2], fp[i], w2);
            pkfma(ac[3], fp[i], w3);
        }
        f2 w0p[4], w1p[4], vap[4], vbp[4];
        {
            float4 wa = *(const float4*)&sW1[jt];
            float4 wb = *(const float4*)&sW1[jt + 4];
            w0p[0].x = wa.x; w0p[0].y = wa.y;
            w0p[1].x = wa.z; w0p[1].y = wa.w;
            w0p[2].x = wb.x; w0p[2].y = wb.y;
            w0p[3].x = wb.z; w0p[3].y = wb.w;
            wa = *(const float4*)&sW1[HID + jt];
            wb = *(const float4*)&sW1[HID + jt + 4];
            w1p[0].x = wa.x; w1p[0].y = wa.y;
            w1p[1].x = wa.z; w1p[1].y = wa.w;
            w1p[2].x = wb.x; w1p[2].y = wb.y;
            w1p[3].x = wb.z; w1p[3].y = wb.w;
            wa = *(const float4*)&sW2a[jt];
            wb = *(const float4*)&sW2a[jt + 4];
            vap[0].x = wa.x; vap[0].y = wa.y;
            vap[1].x = wa.z; vap[1].y = wa.w;
            vap[2].x = wb.x; vap[2].y = wb.y;
            vap[3].x = wb.z; vap[3].y = wb.w;
            wa = *(const float4*)&sW2b[jt];
            wb = *(const float4*)&sW2b[jt + 4];
            vbp[0].x = wa.x; vbp[0].y = wa.y;
            vbp[1].x = wa.z; vbp[1].y = wa.w;
            vbp[2].x = wb.x; vbp[2].y = wb.y;
            vbp[3].x = wb.z; vbp[3].y = wb.w;
        }
#pragma unroll
        for (int k = 0; k < 4; ++k) {
            f2 h;
            h = pkfma3(sa, w1p[k], ac[k]);
            pkfma(h, qa, w0p[k]);
            h.x = fmaxf(h.x, 0.f); h.y = fmaxf(h.y, 0.f);
            pkfma(lA0, h, vap[k]);
            pkfma(lA1, h, vbp[k]);
            h = pkfma3(sb, w1p[k], ac[k]);
            pkfma(h, qb, w0p[k]);
            h.x = fmaxf(h.x, 0.f); h.y = fmaxf(h.y, 0.f);
            pkfma(lB0, h, vap[k]);
            pkfma(lB1, h, vbp[k]);
        }
    }

    {
        float bb0 = b2[0], bb1 = b2[1];
        float la0 = bb0 + lA0.x + lA0.y;
        float la1 = bb1 + lA1.x + lA1.y;
        float lb0 = bb0 + lB0.x + lB0.y;
        float lb1 = bb1 + lB1.x + lB1.y;
        pms[tid] = make_float4(la0, softplusf(la1), lb0, softplusf(lb1));
        sIS[tid] = make_float2(Inv, Snv);
        srid[tid] = make_int2(r0, r1);
        sgid[tid] = act ? g : -1;
    }
    __syncthreads();

    // chunk same-image flags (image_id sorted -> endpoints suffice)
    if (tid < 8) sflag[tid] = (sgid[tid * 32] == sgid[tid * 32 + 31]) ? 1 : 0;

    // ---------- Phase B: 8 lanes per obs, 8 chunks ----------
    int grp = tid >> 3;
    int m4 = tid & 7;

#pragma unroll 2
    for (int c = 0; c < 8; ++c) {
        int o = c * 32 + grp;
        int nn = blockIdx.x * 256 + o;
        if (nn >= N_OBS_C) nn = N_OBS_C - 1;
        int2 rr = srid[o];
        float4 pp = pms[o];
        float2 IS = sIS[o];

        float4 ss = *(const float4*)&seps[(size_t)nn * MC_C + m4 * 4];
        float4 z0, z1;
        {
            const __half2* zp = (const __half2*)(zT + (size_t)rr.x * MC_C + m4 * 4);
            __half2 h0 = zp[0], h1 = zp[1];
            float2 fa = __half22float2(h0), fb = __half22float2(h1);
            z0 = make_float4(fa.x, fa.y, fb.x, fb.y);
            zp = (const __half2*)(zT + (size_t)rr.y * MC_C + m4 * 4);
            h0 = zp[0]; h1 = zp[1];
            fa = __half22float2(h0); fb = __half22float2(h1);
            z1 = make_float4(fa.x, fa.y, fb.x, fb.y);
        }

        float rsig = 1.0f / IS.y;
        float mnIr = -IS.x * rsig;

        float sd20 = 0.f, sip0 = 0.f, sd21 = 0.f, sip1 = 0.f;
#define MCSTEP(zc0, zc1, sc_)                              \
        {                                                  \
            float sc0 = fmaf(pp.y, sc_, pp.x);             \
            float ip0 = zc0 * sc0;                         \
            float d0 = fmaf(ip0, rsig, mnIr);              \
            sd20 = fmaf(d0, d0, sd20);                     \
            sip0 += ip0;                                   \
            float sc1 = fmaf(pp.w, sc_, pp.z);             \
            float ip1 = zc1 * sc1;                         \
            float d1 = fmaf(ip1, rsig, mnIr);              \
            sd21 = fmaf(d1, d1, sd21);                     \
            sip1 += ip1;                                   \
        }
        MCSTEP(z0.x, z1.x, ss.x)
        MCSTEP(z0.y, z1.y, ss.y)
        MCSTEP(z0.z, z1.z, ss.z)
        MCSTEP(z0.w, z1.w, ss.w)
#undef MCSTEP

#pragma unroll
        for (int o2 = 4; o2 > 0; o2 >>= 1) {
            sd20 += __shfl_xor(sd20, o2);
            sd21 += __shfl_xor(sd21, o2);
            sip0 += __shfl_xor(sip0, o2);
            sip1 += __shfl_xor(sip1, o2);
        }

        if (m4 == 0) {
            float logS32 = 32.f * logf(IS.y) + 16.f * LOG2PI_F;
            float y0 = sip0 * (1.0f / 32.0f);
            float y1 = sip1 * (1.0f / 32.0f);
            float w = rsig * rsig;
            float* mr = mom[c][grp];
            mr[0] = -0.5f * sd20 - logS32;
            mr[1] = -0.5f * sd21 - logS32;
            mr[2] = w;
            mr[3] = w * IS.x;
            mr[4] = w * IS.x * IS.x;
            mr[5] = w * y0;
            mr[6] = w * y0 * y0;
            mr[7] = w * IS.x * y0;
            mr[8] = w * y1;
            mr[9] = w * y1 * y1;
            mr[10] = w * IS.x * y1;
            mr[11] = 0.f;
        }
    }
    __syncthreads();

    // ---------- flush: 96 threads = 8 chunks x 12 moments ----------
    if (tid < 96) {
        int c = tid / 12, j = tid - c * 12;
        int slot = blockIdx.x & (NSLOT - 1);
        if (sflag[c]) {
            int g0 = sgid[c * 32];
            if (g0 >= 0) {
                float v = 0.f;
#pragma unroll
                for (int s = 0; s < 32; ++s) v += mom[c][s][j];
                atomicAdd(&img_mom[(g0 * 12 + j) * NSLOT + slot], v);
            }
        } else {
            for (int s = 0; s < 32; ++s) {
                int gs = sgid[c * 32 + s];
                if (gs >= 0)
                    atomicAdd(&img_mom[(gs * 12 + j) * NSLOT + slot], mom[c][s][j]);
            }
        }
    }
}

// ---- K3: per-image slot-sum + argmax + block-reduced global sums ----
__global__ __launch_bounds__(256) void k_img(const float* __restrict__ img_mom,
                                             double* __restrict__ accs) {
    int g = blockIdx.x * 256 + threadIdx.x;
    double red7[7] = {0, 0, 0, 0, 0, 0, 0};
    if (g < N_IMG_C) {
        float M[12];
#pragma unroll
        for (int j = 0; j < 12; ++j) {
            const float4* p = (const float4*)&img_mom[(g * 12 + j) * NSLOT];
            float4 q0 = p[0], q1 = p[1], q2 = p[2], q3 = p[3];
            M[j] = (q0.x + q0.y + q0.z + q0.w) + (q1.x + q1.y + q1.z + q1.w) +
                   (q2.x + q2.y + q2.z + q2.w) + (q3.x + q3.y + q3.z + q3.w);
        }
        float ll0 = M[0] * (1.0f / 32.0f);
        float ll1 = M[1] * (1.0f / 32.0f);
        bool op1 = (ll1 > ll0);
        red7[0] = (double)fmaxf(ll0, ll1);
        red7[1] = (double)M[2];
        red7[2] = (double)M[3];
        red7[3] = (double)(op1 ? M[8] : M[5]);
        red7[4] = (double)M[4];
        red7[5] = (double)(op1 ? M[9] : M[6]);
        red7[6] = (double)(op1 ? M[10] : M[7]);
    }
#pragma unroll
    for (int k = 0; k < 7; ++k)
        for (int o = 32; o > 0; o >>= 1) red7[k] += __shfl_xor(red7[k], o);
    __shared__ double sred[4][7];
    int lane = threadIdx.x & 63, w = threadIdx.x >> 6;
    if (lane == 0) {
#pragma unroll
        for (int k = 0; k < 7; ++k) sred[w][k] = red7[k];
    }
    __syncthreads();
    if (threadIdx.x < 7) {
        double v = sred[0][threadIdx.x] + sred[1][threadIdx.x] +
                   sred[2][threadIdx.x] + sred[3][threadIdx.x];
        atomicAdd(&accs[1 + threadIdx.x], v);
    }
}

// ---- K5: finalize ----
__global__ void k_final(const double* __restrict__ accs, float* __restrict__ out) {
    double kl = accs[0] / (double)N_REFL_C;
    double elbo = -(accs[1] / (double)N_IMG_C) + 1.0 * kl;
    double W = accs[2], Sx = accs[3], Sy = accs[4];
    double Sxx = accs[5], Syy = accs[6], Sxy = accs[7];
    double z = 1.0 / W;
    double mx = z * Sx, my = z * Sy;
    double cxy = z * Sxy - mx * my;
    double cx = z * Sxx - mx * mx;
    double cy = z * Syy - my * my;
    double cc = cxy / sqrt(cx * cy);
    out[0] = (float)elbo;
    out[1] = (float)cc;
}

extern "C" void kernel_launch(void* const* d_in, const int* in_sizes, int n_in,
                              void* d_out, int out_size, void* d_ws, size_t ws_size,
                              hipStream_t stream) {
    const float* I = (const float*)d_in[0];
    const float* SigI = (const float*)d_in[1];
    const int* image_id = (const int*)d_in[2];
    const float* metadata = (const float*)d_in[3];
    const float* wavelength = (const float*)d_in[4];
    const float* dHKL = (const float*)d_in[5];
    const int* refl_ids = (const int*)d_in[6];
    const float* q_loc = (const float*)d_in[7];
    const float* q_scale_raw = (const float*)d_in[8];
    const float* img_emb = (const float*)d_in[9];
    const float* W1 = (const float*)d_in[10];
    const float* b1 = (const float*)d_in[11];
    const float* W2 = (const float*)d_in[12];
    const float* b2 = (const float*)d_in[13];
    const float* zeps = (const float*)d_in[14];
    const float* seps = (const float*)d_in[15];
    float* out = (float*)d_out;

    char* ws = (char*)d_ws;
    double* accs = (double*)ws;
    float* img_mom = (float*)(ws + 64);
    float* sqv = (float*)(ws + 2097152);
    float* img_pre = (float*)(ws + 4194304);
    __half* zT = (__half*)(ws + 8388608);

    k_zero<<<(ZERO_F4 + 255) / 256, 256, 0, stream>>>((float4*)ws);
    k_refl<<<(N_REFL_C + 255) / 256, 256, 0, stream>>>(q_loc, q_scale_raw, zeps,
                                                       sqv, zT, &accs[0]);
    k_imgpre<<<N_IMG_C, 64, 0, stream>>>(img_emb, W1, b1, img_pre);
    k_main<<<(N_OBS_C + 255) / 256, 256, 0, stream>>>(I, SigI, image_id, metadata,
                                                      wavelength, dHKL, refl_ids,
                                                      q_loc, W1, W2, b2, sqv,
                                                      img_pre, seps, zT, img_mom);
    k_img<<<(N_IMG_C + 255) / 256, 256, 0, stream>>>(img_mom, accs);
    k_final<<<1, 1, 0, stream>>>(accs, out);
}